// Round 10
// baseline (387.104 us; speedup 1.0000x reference)
//
#include <hip/hip_runtime.h>
#include <cstdint>
#include <cstddef>

#define T_ 256
#define HN_ 4096
#define H_ 32
#define N_ 128
#define SR_ 6464   // COMB row stride (4096 R + 1024 K + 1024 V + 320 T)

typedef __attribute__((ext_vector_type(8))) short short8;
typedef __attribute__((ext_vector_type(4))) float f32x4;

__device__ __forceinline__ short f2bf(float f) {
    uint32_t u = __builtin_bit_cast(uint32_t, f);
    u = (u + 0x7fffu + ((u >> 16) & 1u)) >> 16;   // RNE f32->bf16
    return (short)u;
}
__device__ __forceinline__ short f2bfc(float f) {  // cheap round-half-up
    return (short)((__builtin_bit_cast(uint32_t, f) + 0x8000u) >> 16);
}
__device__ __forceinline__ short8 cvt8r(float4 lo, float4 hi) {
    short8 v;
    v[0] = f2bfc(lo.x); v[1] = f2bfc(lo.y); v[2] = f2bfc(lo.z); v[3] = f2bfc(lo.w);
    v[4] = f2bfc(hi.x); v[5] = f2bfc(hi.y); v[6] = f2bfc(hi.z); v[7] = f2bfc(hi.w);
    return v;
}
__device__ __forceinline__ f32x4 mfma16(short8 a, short8 b, f32x4 c) {
    return __builtin_amdgcn_mfma_f32_16x16x32_bf16(a, b, c, 0, 0, 0);
}
__device__ __forceinline__ float sigm(float x) { return 1.f / (1.f + expf(-x)); }
__device__ __forceinline__ float splus(float x) { return (x > 20.f) ? x : log1pf(expf(x)); }

__device__ __forceinline__ float bf1(ushort u) {
    return __builtin_bit_cast(float, (uint32_t)u << 16);
}
__device__ __forceinline__ void bf4(float* d, const ushort* p) {
    uint2 u = *(const uint2*)p;
    d[0] = __builtin_bit_cast(float, u.x << 16);
    d[1] = __builtin_bit_cast(float, u.x & 0xffff0000u);
    d[2] = __builtin_bit_cast(float, u.y << 16);
    d[3] = __builtin_bit_cast(float, u.y & 0xffff0000u);
}
__device__ __forceinline__ void gload_lds16(const void* g, void* l) {
    __builtin_amdgcn_global_load_lds(
        (const __attribute__((address_space(1))) void*)g,
        (__attribute__((address_space(3))) void*)l, 16, 0, 0);
}

// ---- LDS-staged pipelined GEMM core (proven R7) --------------------------------
__device__ __forceinline__ void gemm_core(
    const ushort* __restrict__ A, const float* __restrict__ Brow,
    int kbeg, float* LB, f32x4 acc[2][2]) {
    const int tid = threadIdx.x, wid = tid >> 6, l = tid & 63;
    const int ar = l & 15, ak = (l >> 4) * 8;
    const int mBase = wid * 32;

    const int p1 = tid, p2 = tid + 512;
    const int r1 = p1 >> 5, c1 = (p1 & 31) ^ (r1 & 7);
    const int r2 = p2 >> 5, c2 = (p2 & 31) ^ (r2 & 7);
    const float* sb1 = Brow + (size_t)r1 * 4096 + kbeg + c1 * 4;
    const float* sb2 = Brow + (size_t)r2 * 4096 + kbeg + c2 * 4;
    float* d1 = LB + wid * 256;
    float* d2 = LB + 2048 + wid * 256;

    const ushort* pa0 = A + (size_t)(mBase + ar) * 4096 + kbeg + ak;
    const ushort* pa1 = pa0 + (size_t)16 * 4096;

    const int rb0 = ar * 128, rb1 = (16 + ar) * 128;
    const int sx = ar & 7;
    const int cb = (l >> 4) * 2;

    short8 Ae[8], Ao[8];

#define STAGEB(s, rb) { \
    gload_lds16(sb1 + (size_t)(s) * 128, d1 + (rb) * 4096); \
    gload_lds16(sb2 + (size_t)(s) * 128, d2 + (rb) * 4096); }

#define LA(B_, s) { \
    B_[0] = *(const short8*)(pa0 + (size_t)(s) * 128);      \
    B_[1] = *(const short8*)(pa1 + (size_t)(s) * 128);      \
    B_[2] = *(const short8*)(pa0 + (size_t)(s) * 128 + 32); \
    B_[3] = *(const short8*)(pa1 + (size_t)(s) * 128 + 32); \
    B_[4] = *(const short8*)(pa0 + (size_t)(s) * 128 + 64); \
    B_[5] = *(const short8*)(pa1 + (size_t)(s) * 128 + 64); \
    B_[6] = *(const short8*)(pa0 + (size_t)(s) * 128 + 96); \
    B_[7] = *(const short8*)(pa1 + (size_t)(s) * 128 + 96); }

#define CKK(kk, B_, Lb_) { \
    const int cc = (kk) * 8 + cb; \
    float4 l0 = *(const float4*)(Lb_ + rb0 + ((cc ^ sx) * 4)); \
    float4 h0 = *(const float4*)(Lb_ + rb0 + (((cc + 1) ^ sx) * 4)); \
    float4 l1 = *(const float4*)(Lb_ + rb1 + ((cc ^ sx) * 4)); \
    float4 h1 = *(const float4*)(Lb_ + rb1 + (((cc + 1) ^ sx) * 4)); \
    short8 b0 = cvt8r(l0, h0), b1 = cvt8r(l1, h1); \
    acc[0][0] = mfma16(B_[2 * (kk)], b0, acc[0][0]); \
    acc[0][1] = mfma16(B_[2 * (kk)], b1, acc[0][1]); \
    acc[1][0] = mfma16(B_[2 * (kk) + 1], b0, acc[1][0]); \
    acc[1][1] = mfma16(B_[2 * (kk) + 1], b1, acc[1][1]); }

#define COMPUTE(rb, B_) { const float* Lb_ = LB + (rb) * 4096; \
    CKK(0, B_, Lb_) CKK(1, B_, Lb_) CKK(2, B_, Lb_) CKK(3, B_, Lb_) }

    STAGEB(0, 0)
    LA(Ae, 0)
    STAGEB(1, 1)

    for (int su = 0; su < 4; su++) {
        const int s0 = su * 2, s1 = su * 2 + 1;
        LA(Ao, (s0 + 1 < 8) ? s0 + 1 : 7)
        STAGEB((s0 + 2 < 8) ? s0 + 2 : 7, (s0 + 2) % 3)
        asm volatile("s_waitcnt vmcnt(12)" ::: "memory");
        __builtin_amdgcn_s_barrier();
        __builtin_amdgcn_sched_barrier(0);
        COMPUTE(s0 % 3, Ae)
        __builtin_amdgcn_s_barrier();

        LA(Ae, (s1 + 1 < 8) ? s1 + 1 : 7)
        STAGEB((s1 + 2 < 8) ? s1 + 2 : 7, (s1 + 2) % 3)
        asm volatile("s_waitcnt vmcnt(12)" ::: "memory");
        __builtin_amdgcn_s_barrier();
        __builtin_amdgcn_sched_barrier(0);
        COMPUTE(s1 % 3, Ao)
        __builtin_amdgcn_s_barrier();
    }
    asm volatile("s_waitcnt vmcnt(0)" ::: "memory");
#undef STAGEB
#undef LA
#undef CKK
#undef COMPUTE
}

// ---------------- RMSNorm over 4096; optional f32 out, bf16 out, lastrow ----------
__global__ __launch_bounds__(256) void rmsnorm_k(const float* __restrict__ in,
                                                 const float* __restrict__ w,
                                                 float* __restrict__ outF,
                                                 ushort* __restrict__ outB,
                                                 float* __restrict__ lastrow) {
    int t = blockIdx.x, tid = threadIdx.x;
    const float4* in4 = (const float4*)(in + (size_t)t * HN_);
    const float4* w4 = (const float4*)w;
    float4 v[4]; float ss = 0.f;
#pragma unroll
    for (int q = 0; q < 4; q++) {
        v[q] = in4[q * 256 + tid];
        ss += v[q].x * v[q].x + v[q].y * v[q].y + v[q].z * v[q].z + v[q].w * v[q].w;
    }
#pragma unroll
    for (int o = 32; o; o >>= 1) ss += __shfl_down(ss, o);
    __shared__ float red[4];
    if ((tid & 63) == 0) red[tid >> 6] = ss;
    __syncthreads();
    float tot = red[0] + red[1] + red[2] + red[3];
    float sc = rsqrtf(tot * (1.f / HN_) + 1e-6f);
#pragma unroll
    for (int q = 0; q < 4; q++) {
        float4 wv = w4[q * 256 + tid];
        float4 r;
        r.x = wv.x * v[q].x * sc; r.y = wv.y * v[q].y * sc;
        r.z = wv.z * v[q].z * sc; r.w = wv.w * v[q].w * sc;
        int idx = q * 256 + tid;
        if (outF) ((float4*)(outF + (size_t)t * HN_))[idx] = r;
        if (outB) {
            ushort4 b;
            b.x = (ushort)f2bf(r.x); b.y = (ushort)f2bf(r.y);
            b.z = (ushort)f2bf(r.z); b.w = (ushort)f2bf(r.w);
            ((ushort4*)(outB + (size_t)t * HN_))[idx] = b;
        }
        if (lastrow && t == T_ - 1) ((float4*)lastrow)[idx] = r;
    }
}

// ---------------- fused R/K/V/LoRA1 split-K GEMM, atomic epilogue into COMB ------
__global__ __launch_bounds__(512, 2) void gemm_rkvt(
    const ushort* __restrict__ A,
    const float* __restrict__ Rw, const float* __restrict__ Kw,
    const float* __restrict__ Vw, const float* __restrict__ WT,
    float* __restrict__ COMB) {
    __shared__ __align__(16) float LB[12288];
    const int tid = threadIdx.x, wid = tid >> 6, l = tid & 63;
    const int mBase = wid * 32;
    const int nB = blockIdx.x * 32;
    const int kbeg = blockIdx.y * 1024;

    const float* Bp; int brow;
    if (nB < 4096)      { Bp = Rw; brow = nB; }
    else if (nB < 5120) { Bp = Kw; brow = nB - 4096; }
    else if (nB < 6144) { Bp = Vw; brow = nB - 5120; }
    else                { Bp = WT; brow = nB - 6144; }

    f32x4 acc[2][2];
#pragma unroll
    for (int i = 0; i < 2; i++)
#pragma unroll
        for (int j = 0; j < 2; j++) acc[i][j] = f32x4{0.f, 0.f, 0.f, 0.f};

    gemm_core(A, Bp + (size_t)brow * 4096, kbeg, LB, acc);

    const int rl = (l >> 4) * 4, cl = l & 15;
#pragma unroll
    for (int mf = 0; mf < 2; mf++)
#pragma unroll
        for (int nf = 0; nf < 2; nf++)
#pragma unroll
            for (int e = 0; e < 4; e++)
                unsafeAtomicAdd(&COMB[(size_t)(mBase + mf * 16 + rl + e) * SR_ + nB + nf * 16 + cl],
                                acc[mf][nf][e]);
}

// ---------------- O GEMM: xres += YB @ O^T (atomic, split-K) ---------------------
__global__ __launch_bounds__(512, 2) void gemm_o(
    const ushort* __restrict__ A,
    const float* __restrict__ B,
    float* __restrict__ C) {
    __shared__ __align__(16) float LB[12288];
    const int tid = threadIdx.x, wid = tid >> 6, l = tid & 63;
    const int mBase = wid * 32;
    const int nB = blockIdx.x * 32;
    const int kbeg = blockIdx.y * 1024;

    f32x4 acc[2][2];
#pragma unroll
    for (int i = 0; i < 2; i++)
#pragma unroll
        for (int j = 0; j < 2; j++) acc[i][j] = f32x4{0.f, 0.f, 0.f, 0.f};

    gemm_core(A, B + (size_t)nB * 4096, kbeg, LB, acc);

    const int rl = (l >> 4) * 4, cl = l & 15;
#pragma unroll
    for (int mf = 0; mf < 2; mf++)
#pragma unroll
        for (int nf = 0; nf < 2; nf++)
#pragma unroll
            for (int e = 0; e < 4; e++)
                unsafeAtomicAdd(&C[(size_t)(mBase + mf * 16 + rl + e) * 4096 + nB + nf * 16 + cl],
                                acc[mf][nf][e]);
}

// ---------------- fused stage-2 LoRA GEMMs (4 segments via blockIdx.y) -----------
__global__ __launch_bounds__(512) void gemm_s2(
    const ushort* __restrict__ TCB,
    const float* __restrict__ w2, const float* __restrict__ a2,
    const float* __restrict__ v2, const float* __restrict__ g2,
    const float* __restrict__ w0, const float* __restrict__ a0,
    const float* __restrict__ v0,
    float* __restrict__ WPRE, float* __restrict__ APRE,
    float* __restrict__ VGPRE, float* __restrict__ GARR) {
    const int z = blockIdx.y;
    int Aoff, K; const float* B; const float* bias; float* out;
    if (z == 0)      { Aoff = 0;   K = 64;  B = w2; bias = w0;      out = WPRE; }
    else if (z == 1) { Aoff = 64;  K = 64;  B = a2; bias = a0;      out = APRE; }
    else if (z == 2) { Aoff = 128; K = 32;  B = v2; bias = v0;      out = VGPRE; }
    else             { Aoff = 160; K = 128; B = g2; bias = nullptr; out = GARR; }

    const int tid = threadIdx.x, wid = tid >> 6, l = tid & 63;
    const int ar = l & 15, ak = (l >> 4) * 8;
    const int mBase = wid * 32;
    const int nB = blockIdx.x * 32;

    f32x4 acc[2][2];
#pragma unroll
    for (int i = 0; i < 2; i++)
#pragma unroll
        for (int j = 0; j < 2; j++) acc[i][j] = f32x4{0.f, 0.f, 0.f, 0.f};

    for (int k0 = 0; k0 < K; k0 += 32) {
        const ushort* pA = TCB + (size_t)(mBase + ar) * 320 + Aoff + k0 + ak;
        short8 av0 = *(const short8*)pA;
        short8 av1 = *(const short8*)(pA + (size_t)16 * 320);
        short8 bv0, bv1;
#pragma unroll
        for (int e = 0; e < 8; e++) {
            bv0[e] = f2bfc(B[(size_t)(k0 + ak + e) * 4096 + nB + ar]);
            bv1[e] = f2bfc(B[(size_t)(k0 + ak + e) * 4096 + nB + 16 + ar]);
        }
        acc[0][0] = mfma16(av0, bv0, acc[0][0]);
        acc[0][1] = mfma16(av0, bv1, acc[0][1]);
        acc[1][0] = mfma16(av1, bv0, acc[1][0]);
        acc[1][1] = mfma16(av1, bv1, acc[1][1]);
    }
    const int rl = (l >> 4) * 4, cl = l & 15;
#pragma unroll
    for (int mf = 0; mf < 2; mf++)
#pragma unroll
        for (int nf = 0; nf < 2; nf++) {
            int col = nB + nf * 16 + cl;
            float bv = bias ? bias[col] : 0.f;
#pragma unroll
            for (int e = 0; e < 4; e++)
                out[(size_t)(mBase + mf * 16 + rl + e) * 4096 + col] = acc[mf][nf][e] + bv;
        }
}

// ---------------- LoRA-A concat-transpose via LDS tiles -> WT[320][4096] ---------
__global__ __launch_bounds__(256) void wcat2_k(const float* __restrict__ w1p,
                                               const float* __restrict__ a1p,
                                               const float* __restrict__ v1p,
                                               const float* __restrict__ g1p,
                                               float* __restrict__ WT) {
    const int kb = blockIdx.x * 64, tile = blockIdx.y;
    const float* src; int ldw, jo, nb, W;
    if (tile == 0)      { src = w1p; ldw = 64;  jo = 0;  nb = 0;   W = 64; }
    else if (tile == 1) { src = a1p; ldw = 64;  jo = 0;  nb = 64;  W = 64; }
    else if (tile == 2) { src = v1p; ldw = 32;  jo = 0;  nb = 128; W = 32; }
    else if (tile == 3) { src = g1p; ldw = 128; jo = 0;  nb = 160; W = 64; }
    else                { src = g1p; ldw = 128; jo = 64; nb = 224; W = 64; }
    __shared__ float lds[64][65];
    const int ti = threadIdx.x & 63, wi = threadIdx.x >> 6;
    if (ti < W)
        for (int i = wi; i < 64; i += 4)
            lds[i][ti] = src[(size_t)(kb + i) * ldw + jo + ti];
    __syncthreads();
    for (int i2 = wi; i2 < W; i2 += 4)
        WT[(size_t)(nb + i2) * 4096 + kb + ti] = lds[ti][i2];
}

// ---------------- init COMB rows with biases -------------------------------------
__global__ __launch_bounds__(256) void init_comb_k(const float* __restrict__ Rb,
                                                   const float* __restrict__ Kb,
                                                   const float* __restrict__ Vb,
                                                   float* __restrict__ COMB) {
    int t = blockIdx.x;
    for (int c = threadIdx.x; c < SR_; c += 256) {
        float b = (c < 4096) ? Rb[c] : (c < 5120) ? Kb[c - 4096]
                : (c < 6144) ? Vb[c - 5120] : 0.f;
        COMB[(size_t)t * SR_ + c] = b;
    }
}

// ---------------- activations on TCAT cols of COMB -> TCB bf16 [256][320] --------
__global__ __launch_bounds__(256) void act_k(const float* __restrict__ COMB,
                                             ushort* __restrict__ TCB) {
    int idx = blockIdx.x * 256 + threadIdx.x;
    if (idx >= 256 * 288) return;
    int t = idx / 288, c = idx % 288;
    float v = COMB[(size_t)t * SR_ + 6144 + c];
    if (c < 64) v = tanhf(v);
    else if (c >= 160) v = sigm(v);
    TCB[t * 320 + c] = (ushort)f2bf(v);
}

// ---------------- RoPE cos/sin table [T][64] ----------------
__global__ void rope_k(const int* __restrict__ cpos, float* __restrict__ cosT,
                       float* __restrict__ sinT) {
    int idx = blockIdx.x * 256 + threadIdx.x;
    int t = idx >> 6, f = idx & 63;
    float pos = (float)cpos[0] + (float)t;
    float mix = fminf(fmaxf(pos * (1.f / 4096.f), 0.f), 1.f);
    float e = (float)f * (1.f / 64.f);
    float inv_s = exp2f(-13.287712379549449f * e);
    float inv_l = exp2f(-13.287712379549449f - 3.321928094887362f * e);
    float fr = pos * ((1.f - mix) * inv_s + mix * inv_l);
    cosT[idx] = cosf(fr);
    sinT[idx] = sinf(fr);
}

// ---------------- elementwise prep -> packed scan stream SF ----------------------
// SF record per (h,t): 2048 B = bf16 r|k|v|a|b|g (6*128) + f32 decay (128)
__global__ __launch_bounds__(256) void prep_k(
    const float* __restrict__ COMB, const float* __restrict__ wpre,
    const float* __restrict__ apre, const float* __restrict__ vgpre,
    const float* __restrict__ vfirst, const float* __restrict__ garr,
    const float* __restrict__ cosT, const float* __restrict__ sinT,
    const float* __restrict__ lnr, const float* __restrict__ lnk,
    ushort* __restrict__ SFB) {
    int t = blockIdx.x, tid = threadIdx.x;
    int w = tid >> 6, lane = tid & 63;
    float c = cosT[t * 64 + lane], s = sinT[t * 64 + lane];
    float lr0 = lnr[lane], lr1 = lnr[lane + 64];
    float lk0 = lnk[lane], lk1 = lnk[lane + 64];
    const float* r_raw = COMB;
    const float* k_raw = COMB + 4096;
    const float* v_raw = COMB + 5120;
    for (int hb = 0; hb < 8; hb++) {
        int h = hb * 4 + w;
        int kv = h >> 2;
        float r0 = r_raw[(size_t)t * SR_ + h * 128 + lane];
        float r1 = r_raw[(size_t)t * SR_ + h * 128 + 64 + lane];
        float ssum = r0 * r0 + r1 * r1;
#pragma unroll
        for (int o = 32; o; o >>= 1) ssum += __shfl_xor(ssum, o);
        float sc = rsqrtf(ssum * (1.f / 128.f) + 1e-6f);
        float rn0 = lr0 * r0 * sc, rn1 = lr1 * r1 * sc;
        float rr0 = rn0 * c - rn1 * s;
        float rr1 = rn1 * c + rn0 * s;
        float k0 = k_raw[(size_t)t * SR_ + kv * 128 + lane];
        float k1 = k_raw[(size_t)t * SR_ + kv * 128 + 64 + lane];
        float ks = k0 * k0 + k1 * k1;
#pragma unroll
        for (int o = 32; o; o >>= 1) ks += __shfl_xor(ks, o);
        float ksc = rsqrtf(ks * (1.f / 128.f) + 1e-6f);
        float kn0 = lk0 * k0 * ksc, kn1 = lk1 * k1 * ksc;
        float kr0 = kn0 * c - kn1 * s;
        float kr1 = kn1 * c + kn0 * s;
        float nr = kr0 * kr0 + kr1 * kr1;
#pragma unroll
        for (int o = 32; o; o >>= 1) nr += __shfl_xor(nr, o);
        float inv = 1.f / fmaxf(sqrtf(nr), 1e-12f);
        float kk0 = kr0 * inv, kk1 = kr1 * inv;
        int c0 = h * 128 + lane, c1 = c0 + 64;
        size_t tb = (size_t)t * HN_;

        float wv0 = -splus(-wpre[tb + c0]) - 0.5f;
        float wv1 = -splus(-wpre[tb + c1]) - 0.5f;
        float dec0 = expf(-expf(wv0));
        float dec1 = expf(-expf(wv1));
        float av0 = sigm(apre[tb + c0]);
        float av1 = sigm(apre[tb + c1]);
        float vg0 = sigm(vgpre[tb + c0]);
        float vg1 = sigm(vgpre[tb + c1]);
        float vraw0 = v_raw[(size_t)t * SR_ + kv * 128 + lane];
        float vraw1 = v_raw[(size_t)t * SR_ + kv * 128 + 64 + lane];
        float vf0 = vraw0 + (vfirst[tb + c0] - vraw0) * vg0;
        float vf1 = vraw1 + (vfirst[tb + c1] - vraw1) * vg1;

        ushort* sb = SFB + ((size_t)h * T_ + t) * 1024;
        sb[lane]         = (ushort)f2bf(rr0);
        sb[64 + lane]    = (ushort)f2bf(rr1);
        sb[128 + lane]   = (ushort)f2bf(kr0 * (1.f - wv0 + av0));
        sb[192 + lane]   = (ushort)f2bf(kr1 * (1.f - wv1 + av1));
        sb[256 + lane]   = (ushort)f2bf(vf0);
        sb[320 + lane]   = (ushort)f2bf(vf1);
        sb[384 + lane]   = (ushort)f2bf(-kk0);
        sb[448 + lane]   = (ushort)f2bf(-kk1);
        sb[512 + lane]   = (ushort)f2bf(kk0 * av0);
        sb[576 + lane]   = (ushort)f2bf(kk1 * av1);
        sb[640 + lane]   = (ushort)f2bf(garr[tb + c0]);
        sb[704 + lane]   = (ushort)f2bf(garr[tb + c1]);
        float* sw = (float*)(sb + 768);
        sw[lane]      = dec0;
        sw[64 + lane] = dec1;
    }
}

// ---------------- sequential scan: BARRIER-FREE wave-autonomous pipeline ---------
// grid (32 heads, 8 splits) = 256 blocks x 512 threads (8 waves, 2 rows/wave).
// Each wave stages the FULL 2KB record into its PRIVATE LDS ring (8 bufs) via
// 2 global_load_lds/step; per-wave counted vmcnt waits; NO s_barrier in loop.
// Per-step vm queue/wave = [2 loads + 1 y-store] -> steady wait vmcnt(15)
// (robust to store/load issue-order permutation), vmcnt(10) for warm-up.
#define SDEPTH_ 6    // prefetch distance (ring of 8 buffers)
__global__ __launch_bounds__(512) void scan_k(
    const float* __restrict__ state_in,
    const ushort* __restrict__ SFB,
    const float* __restrict__ rk,
    ushort* __restrict__ yb, float* __restrict__ Sout) {
    const int h = blockIdx.x, sp = blockIdx.y;
    const int tid = threadIdx.x;
    const int il = tid >> 5, jq = tid & 31;
    const int i = sp * 16 + il, j0 = jq * 4;
    const int wv = tid >> 6, ln = tid & 63;

    float S[4];
    {
        float4 s4 = *(const float4*)(state_in + ((size_t)h * 128 + i) * 128 + j0);
        S[0] = s4.x; S[1] = s4.y; S[2] = s4.z; S[3] = s4.w;
    }
    float4 rk4 = *(const float4*)(rk + h * 128 + j0);

    // 8 waves x 8 ring buffers x 2048B = 128 KiB
    __shared__ __align__(16) ushort lds_s[8][8][1024];
    const ushort* hbase = SFB + (size_t)h * T_ * 1024;

    auto STAGE = [&](int b, int t) {
        const ushort* src = hbase + (size_t)(t & (T_ - 1)) * 1024 + ln * 8;
        gload_lds16(src,       &lds_s[wv][b][0]);     // bytes [0,1024)
        gload_lds16(src + 512, &lds_s[wv][b][512]);   // bytes [1024,2048)
    };

#pragma unroll
    for (int d = 0; d < SDEPTH_; d++) STAGE(d, d);

    float cpPend = 0.f;
    int bc = 0, bs = SDEPTH_;
    for (int t = 0; t < T_; t++) {
        if (t <= SDEPTH_) asm volatile("s_waitcnt vmcnt(10)" ::: "memory");
        else              asm volatile("s_waitcnt vmcnt(15)" ::: "memory");

        STAGE(bs, t + SDEPTH_);

        const ushort* L = &lds_s[wv][bc][0];
        float r_[4], k_[4], a_[4], b_[4];
        bf4(r_, L + j0);
        bf4(k_, L + 128 + j0);
        bf4(a_, L + 384 + j0);
        bf4(b_, L + 512 + j0);
        float vi = bf1(L[256 + i]);
        float gv = bf1(L[640 + i]);
        const float* Ld = (const float*)(L + 768);
        float4 w4 = *(const float4*)&Ld[j0];

        // finish y for step t-1 (independent chain; interleaves with sa below)
        if (t > 0) {
            float cr = cpPend;
            cr += __shfl_xor(cr, 1);  cr += __shfl_xor(cr, 2);
            cr += __shfl_xor(cr, 4);  cr += __shfl_xor(cr, 8);
            cr += __shfl_xor(cr, 16);
            if (jq == 0)
                yb[(size_t)(t - 1) * HN_ + h * 128 + i] = (ushort)f2bf(cr);
        }

        float sa = fmaf(S[0], a_[0], fmaf(S[1], a_[1], fmaf(S[2], a_[2], S[3] * a_[3])));
        sa += __shfl_xor(sa, 1);  sa += __shfl_xor(sa, 2);
        sa += __shfl_xor(sa, 4);  sa += __shfl_xor(sa, 8);
        sa += __shfl_xor(sa, 16);

        S[0] = fmaf(vi, k_[0], fmaf(sa, b_[0], S[0] * w4.x));
        S[1] = fmaf(vi, k_[1], fmaf(sa, b_[1], S[1] * w4.y));
        S[2] = fmaf(vi, k_[2], fmaf(sa, b_[2], S[2] * w4.z));
        S[3] = fmaf(vi, k_[3], fmaf(sa, b_[3], S[3] * w4.w));

        float od = fmaf(S[0], r_[0], fmaf(S[1], r_[1], fmaf(S[2], r_[2], S[3] * r_[3])));
        float bd = fmaf(r_[0] * k_[0], rk4.x, fmaf(r_[1] * k_[1], rk4.y,
                   fmaf(r_[2] * k_[2], rk4.z, r_[3] * k_[3] * rk4.w)));
        cpPend = fmaf(od, 0.08838834764831845f, bd * vi) * gv;

        bc = (bc + 1) & 7;
        bs = (bs + 1) & 7;
    }

    // tail: reduce and store y[T-1]
    {
        float cr = cpPend;
        cr += __shfl_xor(cr, 1);  cr += __shfl_xor(cr, 2);
        cr += __shfl_xor(cr, 4);  cr += __shfl_xor(cr, 8);
        cr += __shfl_xor(cr, 16);
        if (jq == 0)
            yb[(size_t)(T_ - 1) * HN_ + h * 128 + i] = (ushort)f2bf(cr);
    }

    float* p = Sout + ((size_t)h * 128 + i) * 128 + j0;
    *(float4*)p = make_float4(S[0], S[1], S[2], S[3]);
}

// =====================================================================================
extern "C" void kernel_launch(void* const* d_in, const int* in_sizes, int n_in,
                              void* d_out, int out_size, void* d_ws, size_t ws_size,
                              hipStream_t stream) {
    const float* x_in   = (const float*)d_in[0];
    const float* vfirst = (const float*)d_in[1];
    const float* state  = (const float*)d_in[2];
    const int*   cpos   = (const int*)d_in[3];
    const float* w0 = (const float*)d_in[4];
    const float* w1 = (const float*)d_in[5];
    const float* w2 = (const float*)d_in[6];
    const float* a0 = (const float*)d_in[7];
    const float* a1 = (const float*)d_in[8];
    const float* a2 = (const float*)d_in[9];
    const float* v0 = (const float*)d_in[10];
    const float* v1 = (const float*)d_in[11];
    const float* v2 = (const float*)d_in[12];
    const float* g1 = (const float*)d_in[13];
    const float* g2 = (const float*)d_in[14];
    const float* r_k = (const float*)d_in[15];
    const float* R_ = (const float*)d_in[16];
    const float* K_ = (const float*)d_in[17];
    const float* V_ = (const float*)d_in[18];
    const float* O_ = (const float*)d_in[19];
    const float* Rb = (const float*)d_in[20];
    const float* Kb = (const float*)d_in[21];
    const float* Vb = (const float*)d_in[22];
    const float* ln_r = (const float*)d_in[23];
    const float* ln_k = (const float*)d_in[24];
    const float* ln1 = (const float*)d_in[25];
    const float* ln2 = (const float*)d_in[26];

    float* ws = (float*)d_ws;
    constexpr size_t OFF_XB   = 0;
    constexpr size_t OFF_COMB = 524288;
    constexpr size_t OFF_WT   = 2179072;
    constexpr size_t OFF_TCB  = 3489792;
    constexpr size_t OFF_WPRE = 3530752;
    constexpr size_t OFF_APRE = 4579328;
    constexpr size_t OFF_VGPRE= 5627904;
    constexpr size_t OFF_G    = 6676480;
    constexpr size_t OFF_COS  = 7725056;
    constexpr size_t OFF_SIN  = 7741440;
    constexpr size_t OFF_SF   = 7757824;
    constexpr size_t OFF_YB   = OFF_XB;

    ushort* XB  = (ushort*)(ws + OFF_XB);
    float* COMB = ws + OFF_COMB;
    float* WT   = ws + OFF_WT;
    ushort* TCB = (ushort*)(ws + OFF_TCB);
    float* WPRE = ws + OFF_WPRE;
    float* APRE = ws + OFF_APRE;
    float* VGPRE= ws + OFF_VGPRE;
    float* GARR = ws + OFF_G;
    float* COST = ws + OFF_COS;
    float* SINT = ws + OFF_SIN;
    ushort* SFB = (ushort*)(ws + OFF_SF);
    ushort* YB  = (ushort*)(ws + OFF_YB);

    float* out = (float*)d_out;
    float* out0  = out;
    float* xlast = out + 1048576;
    float* Sfin  = out + 1052672;
    float* vfout = out + 1576960;
    float* xres  = out + 2625536;

    hipMemcpyAsync(vfout, vfirst, (size_t)1048576 * 4, hipMemcpyDeviceToDevice, stream);
    hipMemcpyAsync(xres, x_in, (size_t)1048576 * 4, hipMemcpyDeviceToDevice, stream);

    rmsnorm_k<<<T_, 256, 0, stream>>>(x_in, ln1, nullptr, XB, xlast);

    wcat2_k<<<dim3(64, 5), 256, 0, stream>>>(w1, a1, v1, g1, WT);
    hipMemsetAsync(WT + (size_t)288 * 4096, 0, (size_t)32 * 4096 * 4, stream);
    init_comb_k<<<T_, 256, 0, stream>>>(Rb, Kb, Vb, COMB);

    gemm_rkvt<<<dim3(202, 4), 512, 0, stream>>>(XB, R_, K_, V_, WT, COMB);

    act_k<<<288, 256, 0, stream>>>(COMB, TCB);

    gemm_s2<<<dim3(128, 4), 512, 0, stream>>>(TCB, w2, a2, v2, g2, w0, a0, v0,
                                              WPRE, APRE, VGPRE, GARR);

    rope_k<<<64, 256, 0, stream>>>(cpos, COST, SINT);

    prep_k<<<T_, 256, 0, stream>>>(COMB, WPRE, APRE, VGPRE, vfirst, GARR,
                                   COST, SINT, ln_r, ln_k, SFB);

    scan_k<<<dim3(32, 8), 512, 0, stream>>>(state, SFB, r_k, YB, Sfin);

    gemm_o<<<dim3(128, 4), 512, 0, stream>>>(YB, O_, xres);

    rmsnorm_k<<<T_, 256, 0, stream>>>(xres, ln2, out0, nullptr, nullptr);
}

// Round 11
// 329.317 us; speedup vs baseline: 1.1755x; 1.1755x over previous
//
#include <hip/hip_runtime.h>
#include <cstdint>
#include <cstddef>

#define T_ 256
#define HN_ 4096
#define H_ 32
#define N_ 128
#define SR_ 6464   // COMB row stride (4096 R + 1024 K + 1024 V + 320 T)

typedef __attribute__((ext_vector_type(8))) short short8;
typedef __attribute__((ext_vector_type(4))) float f32x4;

__device__ __forceinline__ short f2bf(float f) {
    uint32_t u = __builtin_bit_cast(uint32_t, f);
    u = (u + 0x7fffu + ((u >> 16) & 1u)) >> 16;   // RNE f32->bf16
    return (short)u;
}
__device__ __forceinline__ short f2bfc(float f) {  // cheap round-half-up
    return (short)((__builtin_bit_cast(uint32_t, f) + 0x8000u) >> 16);
}
__device__ __forceinline__ short8 cvt8r(float4 lo, float4 hi) {
    short8 v;
    v[0] = f2bfc(lo.x); v[1] = f2bfc(lo.y); v[2] = f2bfc(lo.z); v[3] = f2bfc(lo.w);
    v[4] = f2bfc(hi.x); v[5] = f2bfc(hi.y); v[6] = f2bfc(hi.z); v[7] = f2bfc(hi.w);
    return v;
}
__device__ __forceinline__ f32x4 mfma16(short8 a, short8 b, f32x4 c) {
    return __builtin_amdgcn_mfma_f32_16x16x32_bf16(a, b, c, 0, 0, 0);
}
__device__ __forceinline__ float sigm(float x) { return 1.f / (1.f + expf(-x)); }
__device__ __forceinline__ float splus(float x) { return (x > 20.f) ? x : log1pf(expf(x)); }

__device__ __forceinline__ float bf1(ushort u) {
    return __builtin_bit_cast(float, (uint32_t)u << 16);
}
__device__ __forceinline__ void bf4(float* d, const ushort* p) {
    uint2 u = *(const uint2*)p;
    d[0] = __builtin_bit_cast(float, u.x << 16);
    d[1] = __builtin_bit_cast(float, u.x & 0xffff0000u);
    d[2] = __builtin_bit_cast(float, u.y << 16);
    d[3] = __builtin_bit_cast(float, u.y & 0xffff0000u);
}
__device__ __forceinline__ void gload_lds16(const void* g, void* l) {
    __builtin_amdgcn_global_load_lds(
        (const __attribute__((address_space(1))) void*)g,
        (__attribute__((address_space(3))) void*)l, 16, 0, 0);
}

// ---- DPP cross-lane add (VALU pipe, ~2-4cy vs ds_swizzle ~40-120cy) ------------
template <int CTRL>
__device__ __forceinline__ float dpp_add(float v) {
    int p = __builtin_amdgcn_mov_dpp(__builtin_bit_cast(int, v), CTRL, 0xF, 0xF, true);
    return v + __builtin_bit_cast(float, p);
}
// 32-lane reduce-all: 16-lane butterfly via DPP (xor1,xor2 quad_perm; ror4; ror8
// -- after quad_perms each quad is uniform, two rotations sum all quads), then
// one shfl_xor(16) for the half exchange. 1 DS op instead of 5.
__device__ __forceinline__ float reduce32(float v) {
    v = dpp_add<0xB1>(v);     // quad_perm [1,0,3,2]  (xor 1)
    v = dpp_add<0x4E>(v);     // quad_perm [2,3,0,1]  (xor 2)
    v = dpp_add<0x124>(v);    // row_ror:4
    v = dpp_add<0x128>(v);    // row_ror:8
    v += __shfl_xor(v, 16);
    return v;
}

// ---- LDS-staged pipelined GEMM core (proven R7) --------------------------------
__device__ __forceinline__ void gemm_core(
    const ushort* __restrict__ A, const float* __restrict__ Brow,
    int kbeg, float* LB, f32x4 acc[2][2]) {
    const int tid = threadIdx.x, wid = tid >> 6, l = tid & 63;
    const int ar = l & 15, ak = (l >> 4) * 8;
    const int mBase = wid * 32;

    const int p1 = tid, p2 = tid + 512;
    const int r1 = p1 >> 5, c1 = (p1 & 31) ^ (r1 & 7);
    const int r2 = p2 >> 5, c2 = (p2 & 31) ^ (r2 & 7);
    const float* sb1 = Brow + (size_t)r1 * 4096 + kbeg + c1 * 4;
    const float* sb2 = Brow + (size_t)r2 * 4096 + kbeg + c2 * 4;
    float* d1 = LB + wid * 256;
    float* d2 = LB + 2048 + wid * 256;

    const ushort* pa0 = A + (size_t)(mBase + ar) * 4096 + kbeg + ak;
    const ushort* pa1 = pa0 + (size_t)16 * 4096;

    const int rb0 = ar * 128, rb1 = (16 + ar) * 128;
    const int sx = ar & 7;
    const int cb = (l >> 4) * 2;

    short8 Ae[8], Ao[8];

#define STAGEB(s, rb) { \
    gload_lds16(sb1 + (size_t)(s) * 128, d1 + (rb) * 4096); \
    gload_lds16(sb2 + (size_t)(s) * 128, d2 + (rb) * 4096); }

#define LA(B_, s) { \
    B_[0] = *(const short8*)(pa0 + (size_t)(s) * 128);      \
    B_[1] = *(const short8*)(pa1 + (size_t)(s) * 128);      \
    B_[2] = *(const short8*)(pa0 + (size_t)(s) * 128 + 32); \
    B_[3] = *(const short8*)(pa1 + (size_t)(s) * 128 + 32); \
    B_[4] = *(const short8*)(pa0 + (size_t)(s) * 128 + 64); \
    B_[5] = *(const short8*)(pa1 + (size_t)(s) * 128 + 64); \
    B_[6] = *(const short8*)(pa0 + (size_t)(s) * 128 + 96); \
    B_[7] = *(const short8*)(pa1 + (size_t)(s) * 128 + 96); }

#define CKK(kk, B_, Lb_) { \
    const int cc = (kk) * 8 + cb; \
    float4 l0 = *(const float4*)(Lb_ + rb0 + ((cc ^ sx) * 4)); \
    float4 h0 = *(const float4*)(Lb_ + rb0 + (((cc + 1) ^ sx) * 4)); \
    float4 l1 = *(const float4*)(Lb_ + rb1 + ((cc ^ sx) * 4)); \
    float4 h1 = *(const float4*)(Lb_ + rb1 + (((cc + 1) ^ sx) * 4)); \
    short8 b0 = cvt8r(l0, h0), b1 = cvt8r(l1, h1); \
    acc[0][0] = mfma16(B_[2 * (kk)], b0, acc[0][0]); \
    acc[0][1] = mfma16(B_[2 * (kk)], b1, acc[0][1]); \
    acc[1][0] = mfma16(B_[2 * (kk) + 1], b0, acc[1][0]); \
    acc[1][1] = mfma16(B_[2 * (kk) + 1], b1, acc[1][1]); }

#define COMPUTE(rb, B_) { const float* Lb_ = LB + (rb) * 4096; \
    CKK(0, B_, Lb_) CKK(1, B_, Lb_) CKK(2, B_, Lb_) CKK(3, B_, Lb_) }

    STAGEB(0, 0)
    LA(Ae, 0)
    STAGEB(1, 1)

    for (int su = 0; su < 4; su++) {
        const int s0 = su * 2, s1 = su * 2 + 1;
        LA(Ao, (s0 + 1 < 8) ? s0 + 1 : 7)
        STAGEB((s0 + 2 < 8) ? s0 + 2 : 7, (s0 + 2) % 3)
        asm volatile("s_waitcnt vmcnt(12)" ::: "memory");
        __builtin_amdgcn_s_barrier();
        __builtin_amdgcn_sched_barrier(0);
        COMPUTE(s0 % 3, Ae)
        __builtin_amdgcn_s_barrier();

        LA(Ae, (s1 + 1 < 8) ? s1 + 1 : 7)
        STAGEB((s1 + 2 < 8) ? s1 + 2 : 7, (s1 + 2) % 3)
        asm volatile("s_waitcnt vmcnt(12)" ::: "memory");
        __builtin_amdgcn_s_barrier();
        __builtin_amdgcn_sched_barrier(0);
        COMPUTE(s1 % 3, Ao)
        __builtin_amdgcn_s_barrier();
    }
    asm volatile("s_waitcnt vmcnt(0)" ::: "memory");
#undef STAGEB
#undef LA
#undef CKK
#undef COMPUTE
}

// ---------------- RMSNorm over 4096; optional f32 out, bf16 out, lastrow ----------
__global__ __launch_bounds__(256) void rmsnorm_k(const float* __restrict__ in,
                                                 const float* __restrict__ w,
                                                 float* __restrict__ outF,
                                                 ushort* __restrict__ outB,
                                                 float* __restrict__ lastrow) {
    int t = blockIdx.x, tid = threadIdx.x;
    const float4* in4 = (const float4*)(in + (size_t)t * HN_);
    const float4* w4 = (const float4*)w;
    float4 v[4]; float ss = 0.f;
#pragma unroll
    for (int q = 0; q < 4; q++) {
        v[q] = in4[q * 256 + tid];
        ss += v[q].x * v[q].x + v[q].y * v[q].y + v[q].z * v[q].z + v[q].w * v[q].w;
    }
#pragma unroll
    for (int o = 32; o; o >>= 1) ss += __shfl_down(ss, o);
    __shared__ float red[4];
    if ((tid & 63) == 0) red[tid >> 6] = ss;
    __syncthreads();
    float tot = red[0] + red[1] + red[2] + red[3];
    float sc = rsqrtf(tot * (1.f / HN_) + 1e-6f);
#pragma unroll
    for (int q = 0; q < 4; q++) {
        float4 wv = w4[q * 256 + tid];
        float4 r;
        r.x = wv.x * v[q].x * sc; r.y = wv.y * v[q].y * sc;
        r.z = wv.z * v[q].z * sc; r.w = wv.w * v[q].w * sc;
        int idx = q * 256 + tid;
        if (outF) ((float4*)(outF + (size_t)t * HN_))[idx] = r;
        if (outB) {
            ushort4 b;
            b.x = (ushort)f2bf(r.x); b.y = (ushort)f2bf(r.y);
            b.z = (ushort)f2bf(r.z); b.w = (ushort)f2bf(r.w);
            ((ushort4*)(outB + (size_t)t * HN_))[idx] = b;
        }
        if (lastrow && t == T_ - 1) ((float4*)lastrow)[idx] = r;
    }
}

// ---------------- fused R/K/V/LoRA1 split-K GEMM, atomic epilogue into COMB ------
__global__ __launch_bounds__(512, 2) void gemm_rkvt(
    const ushort* __restrict__ A,
    const float* __restrict__ Rw, const float* __restrict__ Kw,
    const float* __restrict__ Vw, const float* __restrict__ WT,
    float* __restrict__ COMB) {
    __shared__ __align__(16) float LB[12288];
    const int tid = threadIdx.x, wid = tid >> 6, l = tid & 63;
    const int mBase = wid * 32;
    const int nB = blockIdx.x * 32;
    const int kbeg = blockIdx.y * 1024;

    const float* Bp; int brow;
    if (nB < 4096)      { Bp = Rw; brow = nB; }
    else if (nB < 5120) { Bp = Kw; brow = nB - 4096; }
    else if (nB < 6144) { Bp = Vw; brow = nB - 5120; }
    else                { Bp = WT; brow = nB - 6144; }

    f32x4 acc[2][2];
#pragma unroll
    for (int i = 0; i < 2; i++)
#pragma unroll
        for (int j = 0; j < 2; j++) acc[i][j] = f32x4{0.f, 0.f, 0.f, 0.f};

    gemm_core(A, Bp + (size_t)brow * 4096, kbeg, LB, acc);

    const int rl = (l >> 4) * 4, cl = l & 15;
#pragma unroll
    for (int mf = 0; mf < 2; mf++)
#pragma unroll
        for (int nf = 0; nf < 2; nf++)
#pragma unroll
            for (int e = 0; e < 4; e++)
                unsafeAtomicAdd(&COMB[(size_t)(mBase + mf * 16 + rl + e) * SR_ + nB + nf * 16 + cl],
                                acc[mf][nf][e]);
}

// ---------------- O GEMM: xres += YB @ O^T (atomic, split-K) ---------------------
__global__ __launch_bounds__(512, 2) void gemm_o(
    const ushort* __restrict__ A,
    const float* __restrict__ B,
    float* __restrict__ C) {
    __shared__ __align__(16) float LB[12288];
    const int tid = threadIdx.x, wid = tid >> 6, l = tid & 63;
    const int mBase = wid * 32;
    const int nB = blockIdx.x * 32;
    const int kbeg = blockIdx.y * 1024;

    f32x4 acc[2][2];
#pragma unroll
    for (int i = 0; i < 2; i++)
#pragma unroll
        for (int j = 0; j < 2; j++) acc[i][j] = f32x4{0.f, 0.f, 0.f, 0.f};

    gemm_core(A, B + (size_t)nB * 4096, kbeg, LB, acc);

    const int rl = (l >> 4) * 4, cl = l & 15;
#pragma unroll
    for (int mf = 0; mf < 2; mf++)
#pragma unroll
        for (int nf = 0; nf < 2; nf++)
#pragma unroll
            for (int e = 0; e < 4; e++)
                unsafeAtomicAdd(&C[(size_t)(mBase + mf * 16 + rl + e) * 4096 + nB + nf * 16 + cl],
                                acc[mf][nf][e]);
}

// ---------------- fused stage-2 LoRA GEMMs (4 segments via blockIdx.y) -----------
__global__ __launch_bounds__(512) void gemm_s2(
    const ushort* __restrict__ TCB,
    const float* __restrict__ w2, const float* __restrict__ a2,
    const float* __restrict__ v2, const float* __restrict__ g2,
    const float* __restrict__ w0, const float* __restrict__ a0,
    const float* __restrict__ v0,
    float* __restrict__ WPRE, float* __restrict__ APRE,
    float* __restrict__ VGPRE, float* __restrict__ GARR) {
    const int z = blockIdx.y;
    int Aoff, K; const float* B; const float* bias; float* out;
    if (z == 0)      { Aoff = 0;   K = 64;  B = w2; bias = w0;      out = WPRE; }
    else if (z == 1) { Aoff = 64;  K = 64;  B = a2; bias = a0;      out = APRE; }
    else if (z == 2) { Aoff = 128; K = 32;  B = v2; bias = v0;      out = VGPRE; }
    else             { Aoff = 160; K = 128; B = g2; bias = nullptr; out = GARR; }

    const int tid = threadIdx.x, wid = tid >> 6, l = tid & 63;
    const int ar = l & 15, ak = (l >> 4) * 8;
    const int mBase = wid * 32;
    const int nB = blockIdx.x * 32;

    f32x4 acc[2][2];
#pragma unroll
    for (int i = 0; i < 2; i++)
#pragma unroll
        for (int j = 0; j < 2; j++) acc[i][j] = f32x4{0.f, 0.f, 0.f, 0.f};

    for (int k0 = 0; k0 < K; k0 += 32) {
        const ushort* pA = TCB + (size_t)(mBase + ar) * 320 + Aoff + k0 + ak;
        short8 av0 = *(const short8*)pA;
        short8 av1 = *(const short8*)(pA + (size_t)16 * 320);
        short8 bv0, bv1;
#pragma unroll
        for (int e = 0; e < 8; e++) {
            bv0[e] = f2bfc(B[(size_t)(k0 + ak + e) * 4096 + nB + ar]);
            bv1[e] = f2bfc(B[(size_t)(k0 + ak + e) * 4096 + nB + 16 + ar]);
        }
        acc[0][0] = mfma16(av0, bv0, acc[0][0]);
        acc[0][1] = mfma16(av0, bv1, acc[0][1]);
        acc[1][0] = mfma16(av1, bv0, acc[1][0]);
        acc[1][1] = mfma16(av1, bv1, acc[1][1]);
    }
    const int rl = (l >> 4) * 4, cl = l & 15;
#pragma unroll
    for (int mf = 0; mf < 2; mf++)
#pragma unroll
        for (int nf = 0; nf < 2; nf++) {
            int col = nB + nf * 16 + cl;
            float bv = bias ? bias[col] : 0.f;
#pragma unroll
            for (int e = 0; e < 4; e++)
                out[(size_t)(mBase + mf * 16 + rl + e) * 4096 + col] = acc[mf][nf][e] + bv;
        }
}

// ---------------- LoRA-A concat-transpose via LDS tiles -> WT[320][4096] ---------
__global__ __launch_bounds__(256) void wcat2_k(const float* __restrict__ w1p,
                                               const float* __restrict__ a1p,
                                               const float* __restrict__ v1p,
                                               const float* __restrict__ g1p,
                                               float* __restrict__ WT) {
    const int kb = blockIdx.x * 64, tile = blockIdx.y;
    const float* src; int ldw, jo, nb, W;
    if (tile == 0)      { src = w1p; ldw = 64;  jo = 0;  nb = 0;   W = 64; }
    else if (tile == 1) { src = a1p; ldw = 64;  jo = 0;  nb = 64;  W = 64; }
    else if (tile == 2) { src = v1p; ldw = 32;  jo = 0;  nb = 128; W = 32; }
    else if (tile == 3) { src = g1p; ldw = 128; jo = 0;  nb = 160; W = 64; }
    else                { src = g1p; ldw = 128; jo = 64; nb = 224; W = 64; }
    __shared__ float lds[64][65];
    const int ti = threadIdx.x & 63, wi = threadIdx.x >> 6;
    if (ti < W)
        for (int i = wi; i < 64; i += 4)
            lds[i][ti] = src[(size_t)(kb + i) * ldw + jo + ti];
    __syncthreads();
    for (int i2 = wi; i2 < W; i2 += 4)
        WT[(size_t)(nb + i2) * 4096 + kb + ti] = lds[ti][i2];
}

// ---------------- init COMB rows with biases -------------------------------------
__global__ __launch_bounds__(256) void init_comb_k(const float* __restrict__ Rb,
                                                   const float* __restrict__ Kb,
                                                   const float* __restrict__ Vb,
                                                   float* __restrict__ COMB) {
    int t = blockIdx.x;
    for (int c = threadIdx.x; c < SR_; c += 256) {
        float b = (c < 4096) ? Rb[c] : (c < 5120) ? Kb[c - 4096]
                : (c < 6144) ? Vb[c - 5120] : 0.f;
        COMB[(size_t)t * SR_ + c] = b;
    }
}

// ---------------- activations on TCAT cols of COMB -> TCB bf16 [256][320] --------
__global__ __launch_bounds__(256) void act_k(const float* __restrict__ COMB,
                                             ushort* __restrict__ TCB) {
    int idx = blockIdx.x * 256 + threadIdx.x;
    if (idx >= 256 * 288) return;
    int t = idx / 288, c = idx % 288;
    float v = COMB[(size_t)t * SR_ + 6144 + c];
    if (c < 64) v = tanhf(v);
    else if (c >= 160) v = sigm(v);
    TCB[t * 320 + c] = (ushort)f2bf(v);
}

// ---------------- RoPE cos/sin table [T][64] ----------------
__global__ void rope_k(const int* __restrict__ cpos, float* __restrict__ cosT,
                       float* __restrict__ sinT) {
    int idx = blockIdx.x * 256 + threadIdx.x;
    int t = idx >> 6, f = idx & 63;
    float pos = (float)cpos[0] + (float)t;
    float mix = fminf(fmaxf(pos * (1.f / 4096.f), 0.f), 1.f);
    float e = (float)f * (1.f / 64.f);
    float inv_s = exp2f(-13.287712379549449f * e);
    float inv_l = exp2f(-13.287712379549449f - 3.321928094887362f * e);
    float fr = pos * ((1.f - mix) * inv_s + mix * inv_l);
    cosT[idx] = cosf(fr);
    sinT[idx] = sinf(fr);
}

// ---------------- elementwise prep -> packed scan stream SF ----------------------
// SF record per (h,t): 2048 B = bf16 r|k|v|a|b|g (6*128) + f32 decay (128)
__global__ __launch_bounds__(256) void prep_k(
    const float* __restrict__ COMB, const float* __restrict__ wpre,
    const float* __restrict__ apre, const float* __restrict__ vgpre,
    const float* __restrict__ vfirst, const float* __restrict__ garr,
    const float* __restrict__ cosT, const float* __restrict__ sinT,
    const float* __restrict__ lnr, const float* __restrict__ lnk,
    ushort* __restrict__ SFB) {
    int t = blockIdx.x, tid = threadIdx.x;
    int w = tid >> 6, lane = tid & 63;
    float c = cosT[t * 64 + lane], s = sinT[t * 64 + lane];
    float lr0 = lnr[lane], lr1 = lnr[lane + 64];
    float lk0 = lnk[lane], lk1 = lnk[lane + 64];
    const float* r_raw = COMB;
    const float* k_raw = COMB + 4096;
    const float* v_raw = COMB + 5120;
    for (int hb = 0; hb < 8; hb++) {
        int h = hb * 4 + w;
        int kv = h >> 2;
        float r0 = r_raw[(size_t)t * SR_ + h * 128 + lane];
        float r1 = r_raw[(size_t)t * SR_ + h * 128 + 64 + lane];
        float ssum = r0 * r0 + r1 * r1;
#pragma unroll
        for (int o = 32; o; o >>= 1) ssum += __shfl_xor(ssum, o);
        float sc = rsqrtf(ssum * (1.f / 128.f) + 1e-6f);
        float rn0 = lr0 * r0 * sc, rn1 = lr1 * r1 * sc;
        float rr0 = rn0 * c - rn1 * s;
        float rr1 = rn1 * c + rn0 * s;
        float k0 = k_raw[(size_t)t * SR_ + kv * 128 + lane];
        float k1 = k_raw[(size_t)t * SR_ + kv * 128 + 64 + lane];
        float ks = k0 * k0 + k1 * k1;
#pragma unroll
        for (int o = 32; o; o >>= 1) ks += __shfl_xor(ks, o);
        float ksc = rsqrtf(ks * (1.f / 128.f) + 1e-6f);
        float kn0 = lk0 * k0 * ksc, kn1 = lk1 * k1 * ksc;
        float kr0 = kn0 * c - kn1 * s;
        float kr1 = kn1 * c + kn0 * s;
        float nr = kr0 * kr0 + kr1 * kr1;
#pragma unroll
        for (int o = 32; o; o >>= 1) nr += __shfl_xor(nr, o);
        float inv = 1.f / fmaxf(sqrtf(nr), 1e-12f);
        float kk0 = kr0 * inv, kk1 = kr1 * inv;
        int c0 = h * 128 + lane, c1 = c0 + 64;
        size_t tb = (size_t)t * HN_;

        float wv0 = -splus(-wpre[tb + c0]) - 0.5f;
        float wv1 = -splus(-wpre[tb + c1]) - 0.5f;
        float dec0 = expf(-expf(wv0));
        float dec1 = expf(-expf(wv1));
        float av0 = sigm(apre[tb + c0]);
        float av1 = sigm(apre[tb + c1]);
        float vg0 = sigm(vgpre[tb + c0]);
        float vg1 = sigm(vgpre[tb + c1]);
        float vraw0 = v_raw[(size_t)t * SR_ + kv * 128 + lane];
        float vraw1 = v_raw[(size_t)t * SR_ + kv * 128 + 64 + lane];
        float vf0 = vraw0 + (vfirst[tb + c0] - vraw0) * vg0;
        float vf1 = vraw1 + (vfirst[tb + c1] - vraw1) * vg1;

        ushort* sb = SFB + ((size_t)h * T_ + t) * 1024;
        sb[lane]         = (ushort)f2bf(rr0);
        sb[64 + lane]    = (ushort)f2bf(rr1);
        sb[128 + lane]   = (ushort)f2bf(kr0 * (1.f - wv0 + av0));
        sb[192 + lane]   = (ushort)f2bf(kr1 * (1.f - wv1 + av1));
        sb[256 + lane]   = (ushort)f2bf(vf0);
        sb[320 + lane]   = (ushort)f2bf(vf1);
        sb[384 + lane]   = (ushort)f2bf(-kk0);
        sb[448 + lane]   = (ushort)f2bf(-kk1);
        sb[512 + lane]   = (ushort)f2bf(kk0 * av0);
        sb[576 + lane]   = (ushort)f2bf(kk1 * av1);
        sb[640 + lane]   = (ushort)f2bf(garr[tb + c0]);
        sb[704 + lane]   = (ushort)f2bf(garr[tb + c1]);
        float* sw = (float*)(sb + 768);
        sw[lane]      = dec0;
        sw[64 + lane] = dec1;
    }
}

// ---------------- sequential scan: R8 shell + DPP reductions ---------------------
// grid (32 heads, 8 splits) = 256 blocks x 512 threads (16 rows x 32 jq).
// Waves 0,1 stage (counted vmcnt(7)); wave 7 flushes y (never stages).
// cp partial computed at step t, reduced at t+1. Reductions: 4 DPP + 1 shfl.
#define SD_ 8     // pipeline depth
#define SNB_ 9    // ring buffers = SD_+1
__global__ __launch_bounds__(512) void scan_k(
    const float* __restrict__ state_in,
    const ushort* __restrict__ SFB,
    const float* __restrict__ rk,
    ushort* __restrict__ yb, float* __restrict__ Sout) {
    const int h = blockIdx.x, sp = blockIdx.y;
    const int tid = threadIdx.x;
    const int il = tid >> 5, jq = tid & 31;
    const int i = sp * 16 + il, j0 = jq * 4;
    const int wv = tid >> 6;

    float S[4];
    {
        float4 s4 = *(const float4*)(state_in + ((size_t)h * 128 + i) * 128 + j0);
        S[0] = s4.x; S[1] = s4.y; S[2] = s4.z; S[3] = s4.w;
    }
    float4 rk4 = *(const float4*)(rk + h * 128 + j0);

    __shared__ __align__(16) ushort lds_s[SNB_][1024];
    __shared__ float ybuf[2][16];
    const ushort* hbase = SFB + (size_t)h * T_ * 1024;

    auto STAGE = [&](int buf, int t) {
        if (tid < 128) {
            const ushort* src = hbase + (size_t)(t & (T_ - 1)) * 1024 + tid * 8;
            gload_lds16(src, &lds_s[buf][wv * 512]);
        }
    };

#pragma unroll
    for (int d = 0; d < SD_; d++) STAGE(d, d);

    float cpPend = 0.f;
    int bc = 0, bs = SD_;
    for (int t = 0; t < T_; t++) {
        if (wv < 2) asm volatile("s_waitcnt vmcnt(7)" ::: "memory");
        __builtin_amdgcn_s_barrier();
        __builtin_amdgcn_sched_barrier(0);
        asm volatile("" ::: "memory");

        STAGE(bs, t + SD_);

        // flush y for step t-2 (wave 7 never stages -> vmcnt count intact)
        if (wv == 7 && (tid & 63) < 16 && t > 1) {
            int ln = tid & 63;
            yb[(size_t)(t - 2) * HN_ + h * 128 + sp * 16 + ln] =
                (ushort)f2bf(ybuf[t & 1][ln]);
        }

        // finish cp reduce for step t-1 (independent of this step's sa chain)
        if (t > 0) {
            float cr = reduce32(cpPend);
            if (jq == 0) ybuf[(t - 1) & 1][il] = cr;
        }

        const ushort* L = lds_s[bc];
        float r_[4], k_[4], a_[4], b_[4];
        bf4(r_, L + j0);
        bf4(k_, L + 128 + j0);
        bf4(a_, L + 384 + j0);
        bf4(b_, L + 512 + j0);
        float vi = bf1(L[256 + i]);
        float gv = bf1(L[640 + i]);
        const float* Ld = (const float*)(L + 768);
        float4 w4 = *(const float4*)&Ld[j0];

        float sa = fmaf(S[0], a_[0], fmaf(S[1], a_[1], fmaf(S[2], a_[2], S[3] * a_[3])));
        sa = reduce32(sa);

        S[0] = fmaf(vi, k_[0], fmaf(sa, b_[0], S[0] * w4.x));
        S[1] = fmaf(vi, k_[1], fmaf(sa, b_[1], S[1] * w4.y));
        S[2] = fmaf(vi, k_[2], fmaf(sa, b_[2], S[2] * w4.z));
        S[3] = fmaf(vi, k_[3], fmaf(sa, b_[3], S[3] * w4.w));

        float od = fmaf(S[0], r_[0], fmaf(S[1], r_[1], fmaf(S[2], r_[2], S[3] * r_[3])));
        float bd = fmaf(r_[0] * k_[0], rk4.x, fmaf(r_[1] * k_[1], rk4.y,
                   fmaf(r_[2] * k_[2], rk4.z, r_[3] * k_[3] * rk4.w)));
        cpPend = fmaf(od, 0.08838834764831845f, bd * vi) * gv;   // gv folded here

        bc = (bc + 1 == SNB_) ? 0 : bc + 1;
        bs = (bs + 1 == SNB_) ? 0 : bs + 1;
    }

    // tail: reduce step T-1, flush steps T-2 and T-1
    __builtin_amdgcn_s_barrier();
    {
        float cr = reduce32(cpPend);
        if (jq == 0)
            yb[(size_t)(T_ - 1) * HN_ + h * 128 + i] = (ushort)f2bf(cr);
    }
    if (wv == 7 && (tid & 63) < 16) {
        int ln = tid & 63;
        yb[(size_t)(T_ - 2) * HN_ + h * 128 + sp * 16 + ln] =
            (ushort)f2bf(ybuf[(T_ - 2) & 1][ln]);
    }

    float* p = Sout + ((size_t)h * 128 + i) * 128 + j0;
    *(float4*)p = make_float4(S[0], S[1], S[2], S[3]);
}

// =====================================================================================
extern "C" void kernel_launch(void* const* d_in, const int* in_sizes, int n_in,
                              void* d_out, int out_size, void* d_ws, size_t ws_size,
                              hipStream_t stream) {
    const float* x_in   = (const float*)d_in[0];
    const float* vfirst = (const float*)d_in[1];
    const float* state  = (const float*)d_in[2];
    const int*   cpos   = (const int*)d_in[3];
    const float* w0 = (const float*)d_in[4];
    const float* w1 = (const float*)d_in[5];
    const float* w2 = (const float*)d_in[6];
    const float* a0 = (const float*)d_in[7];
    const float* a1 = (const float*)d_in[8];
    const float* a2 = (const float*)d_in[9];
    const float* v0 = (const float*)d_in[10];
    const float* v1 = (const float*)d_in[11];
    const float* v2 = (const float*)d_in[12];
    const float* g1 = (const float*)d_in[13];
    const float* g2 = (const float*)d_in[14];
    const float* r_k = (const float*)d_in[15];
    const float* R_ = (const float*)d_in[16];
    const float* K_ = (const float*)d_in[17];
    const float* V_ = (const float*)d_in[18];
    const float* O_ = (const float*)d_in[19];
    const float* Rb = (const float*)d_in[20];
    const float* Kb = (const float*)d_in[21];
    const float* Vb = (const float*)d_in[22];
    const float* ln_r = (const float*)d_in[23];
    const float* ln_k = (const float*)d_in[24];
    const float* ln1 = (const float*)d_in[25];
    const float* ln2 = (const float*)d_in[26];

    float* ws = (float*)d_ws;
    constexpr size_t OFF_XB   = 0;
    constexpr size_t OFF_COMB = 524288;
    constexpr size_t OFF_WT   = 2179072;
    constexpr size_t OFF_TCB  = 3489792;
    constexpr size_t OFF_WPRE = 3530752;
    constexpr size_t OFF_APRE = 4579328;
    constexpr size_t OFF_VGPRE= 5627904;
    constexpr size_t OFF_G    = 6676480;
    constexpr size_t OFF_COS  = 7725056;
    constexpr size_t OFF_SIN  = 7741440;
    constexpr size_t OFF_SF   = 7757824;
    constexpr size_t OFF_YB   = OFF_XB;

    ushort* XB  = (ushort*)(ws + OFF_XB);
    float* COMB = ws + OFF_COMB;
    float* WT   = ws + OFF_WT;
    ushort* TCB = (ushort*)(ws + OFF_TCB);
    float* WPRE = ws + OFF_WPRE;
    float* APRE = ws + OFF_APRE;
    float* VGPRE= ws + OFF_VGPRE;
    float* GARR = ws + OFF_G;
    float* COST = ws + OFF_COS;
    float* SINT = ws + OFF_SIN;
    ushort* SFB = (ushort*)(ws + OFF_SF);
    ushort* YB  = (ushort*)(ws + OFF_YB);

    float* out = (float*)d_out;
    float* out0  = out;
    float* xlast = out + 1048576;
    float* Sfin  = out + 1052672;
    float* vfout = out + 1576960;
    float* xres  = out + 2625536;

    hipMemcpyAsync(vfout, vfirst, (size_t)1048576 * 4, hipMemcpyDeviceToDevice, stream);
    hipMemcpyAsync(xres, x_in, (size_t)1048576 * 4, hipMemcpyDeviceToDevice, stream);

    rmsnorm_k<<<T_, 256, 0, stream>>>(x_in, ln1, nullptr, XB, xlast);

    wcat2_k<<<dim3(64, 5), 256, 0, stream>>>(w1, a1, v1, g1, WT);
    hipMemsetAsync(WT + (size_t)288 * 4096, 0, (size_t)32 * 4096 * 4, stream);
    init_comb_k<<<T_, 256, 0, stream>>>(Rb, Kb, Vb, COMB);

    gemm_rkvt<<<dim3(202, 4), 512, 0, stream>>>(XB, R_, K_, V_, WT, COMB);

    act_k<<<288, 256, 0, stream>>>(COMB, TCB);

    gemm_s2<<<dim3(128, 4), 512, 0, stream>>>(TCB, w2, a2, v2, g2, w0, a0, v0,
                                              WPRE, APRE, VGPRE, GARR);

    rope_k<<<64, 256, 0, stream>>>(cpos, COST, SINT);

    prep_k<<<T_, 256, 0, stream>>>(COMB, WPRE, APRE, VGPRE, vfirst, GARR,
                                   COST, SINT, ln_r, ln_k, SFB);

    scan_k<<<dim3(32, 8), 512, 0, stream>>>(state, SFB, r_k, YB, Sfin);

    gemm_o<<<dim3(128, 4), 512, 0, stream>>>(YB, O_, xres);

    rmsnorm_k<<<T_, 256, 0, stream>>>(xres, ln2, out0, nullptr, nullptr);
}